// Round 7
// baseline (530.087 us; speedup 1.0000x reference)
//
#include <hip/hip_runtime.h>
#include <math.h>

#define DH 128
#define EPSB 1e-5f
#define MAXB 832     // max buckets (N <= 106496)
#define BCAP 3072    // bucket capacity (mean ~2046 at E/N=16)

typedef __attribute__((ext_vector_type(8))) short short8;
typedef __attribute__((ext_vector_type(4))) float f32x4;

static __device__ __forceinline__ unsigned short f2bf(float f) {
    unsigned u = __float_as_uint(f);
    u += 0x7fffu + ((u >> 16) & 1u);
    return (unsigned short)(u >> 16);
}
static __device__ __forceinline__ float bf2f(unsigned short h) {
    return __uint_as_float(((unsigned)h) << 16);
}

// ---------------- bucketed CSR build (+ fused graph-boundary pass) ----------------
// pass A: partition edges into buckets of 128 dsts; packed entry (src<<7)|dlocal

__launch_bounds__(256)
__global__ void k_bucketA(const int* __restrict__ src, const int* __restrict__ dst,
                          int* __restrict__ gcur, int* __restrict__ bbuf,
                          const int* __restrict__ batch, int* __restrict__ starts,
                          int E, int NB, int chunk, int N, int G)
{
    __shared__ int cnt[MAXB];
    __shared__ int base[MAXB];
    const int t = threadIdx.x;

    // fused: graph boundaries (independent work, grid-strided)
    for (int i = blockIdx.x * 256 + t; i < N; i += gridDim.x * 256) {
        int b = batch[i];
        if (i == 0) { starts[0] = 0; starts[G] = N; }
        else if (batch[i - 1] != b) starts[b] = i;
    }

    for (int i = t; i < NB; i += 256) cnt[i] = 0;
    __syncthreads();
    const int e0 = blockIdx.x * chunk;
    const int e1 = min(E, e0 + chunk);
    for (int e = e0 + t; e < e1; e += 256)
        atomicAdd(&cnt[dst[e] >> 7], 1);
    __syncthreads();
    for (int i = t; i < NB; i += 256) {
        int c = cnt[i];
        base[i] = (c > 0) ? atomicAdd(&gcur[i], c) : 0;
        cnt[i] = 0;
    }
    __syncthreads();
    for (int e = e0 + t; e < e1; e += 256) {
        int d = dst[e];
        int b = d >> 7;
        int o = base[b] + atomicAdd(&cnt[b], 1);
        if (o < BCAP) bbuf[(size_t)b * BCAP + o] = (src[e] << 7) | (d & 127);
    }
}

// pass B: single-block exclusive scan of bucket counts -> bucket_base; rowptr[N]=E
__launch_bounds__(1024)
__global__ void k_bgscan(const int* __restrict__ gcur, int* __restrict__ bbase,
                         int* __restrict__ rowptr, int NB, int N, int E)
{
    __shared__ int s[1024];
    int t = threadIdx.x;
    int v = (t < NB) ? min(gcur[t], BCAP) : 0;
    s[t] = v;
    __syncthreads();
    for (int off = 1; off < 1024; off <<= 1) {
        int u = (t >= off) ? s[t - off] : 0;
        __syncthreads();
        s[t] += u;
        __syncthreads();
    }
    if (t < NB) bbase[t] = s[t] - v;   // exclusive
    if (t == 0) rowptr[N] = E;
}

// pass C: per-bucket: deg count, dinv, rowptr, csr scatter (bucket staged in LDS)
__launch_bounds__(256)
__global__ void k_bfinal(const int* __restrict__ gcur, const int* __restrict__ bbase,
                         const int* __restrict__ bbuf, int* __restrict__ rowptr,
                         float* __restrict__ dinv, int* __restrict__ csr_src, int N)
{
    __shared__ int ebuf[BCAP];
    __shared__ int dcnt[128];
    __shared__ int sp[128];
    const int b = blockIdx.x, t = threadIdx.x;
    const int c = min(gcur[b], BCAP);
    const int base = bbase[b];
    const int* p = bbuf + (size_t)b * BCAP;
    for (int i = t; i < c; i += 256) ebuf[i] = p[i];
    if (t < 128) dcnt[t] = 0;
    __syncthreads();
    for (int i = t; i < c; i += 256) atomicAdd(&dcnt[ebuf[i] & 127], 1);
    __syncthreads();
    if (t < 128) sp[t] = dcnt[t];
    __syncthreads();
    for (int off = 1; off < 128; off <<= 1) {
        int u = (t < 128 && t >= off) ? sp[t - off] : 0;
        __syncthreads();
        if (t < 128) sp[t] += u;
        __syncthreads();
    }
    if (t < 128) {
        sp[t] -= dcnt[t];                 // exclusive
        int d = b * 128 + t;
        if (d < N) {
            rowptr[d] = base + sp[t];
            dinv[d] = rsqrtf((float)(dcnt[t] + 1));
        }
        dcnt[t] = 0;                      // reuse as cursor
    }
    __syncthreads();
    for (int i = t; i < c; i += 256) {
        int e = ebuf[i];
        int dl = e & 127;
        int o = atomicAdd(&dcnt[dl], 1);
        csr_src[base + sp[dl] + o] = e >> 7;
    }
}

// ---------------- W fragmentize + bf16 split (all 3 layers, 48 blocks x 256) ----------------
// Frag f = ((nh*2+p)*4+s)*4+nt; lane holds B[k=s*32+quad*8+j][n=nh*64+nt*16+(lane&15)]

__global__ void k_wfrag(const float* __restrict__ W0, const float* __restrict__ W1,
                        const float* __restrict__ W2, unsigned short* __restrict__ Wf0) {
    int fid = blockIdx.x * 4 + (threadIdx.x >> 6);   // 0..191
    int lane = threadIdx.x & 63;
    int l = fid >> 6;
    int f = fid & 63;
    const float* W = (l == 0) ? W0 : (l == 1) ? W1 : W2;
    unsigned short* Wf = Wf0 + (size_t)l * 32768;
    int nt = f & 3, s = (f >> 2) & 3, p = (f >> 4) & 1, nh = f >> 5;
    int n = nh * 64 + nt * 16 + (lane & 15);
    int kbase = s * 32 + (lane >> 4) * 8;
    unsigned short o[8];
#pragma unroll
    for (int j = 0; j < 8; ++j) {
        float w = W[(size_t)(kbase + j) * DH + n];
        unsigned short h = f2bf(w);
        o[j] = p ? f2bf(w - bf2f(h)) : h;
    }
    unsigned short* d = Wf + (size_t)f * 512 + lane * 8;
    *(ushort4*)d       = make_ushort4(o[0], o[1], o[2], o[3]);
    *(ushort4*)(d + 4) = make_ushort4(o[4], o[5], o[6], o[7]);
}

// ---------------- GEMM variant 0 (layer 0): fp32 X, in-register split ----------------
// padded LDS: 64 rows x 132 floats (row stride 528 B -> 2-way bank alias, free)

#define LDA0 132

__launch_bounds__(256)
__global__ void k_gemm0(const float* __restrict__ X,
                        const unsigned short* __restrict__ Wf,
                        const float* __restrict__ dinv,
                        unsigned short* __restrict__ hs, int N)
{
    __shared__ float As[64 * LDA0];

    const int tid  = threadIdx.x;
    const int lane = tid & 63, wave = tid >> 6;
    const int mh = wave >> 1, nh = wave & 1;
    const int rowBase = blockIdx.x * 64;
    const int r15 = lane & 15, quad = lane >> 4;

    {
        const float4* gp = (const float4*)(X + (size_t)rowBase * DH);
#pragma unroll
        for (int it = 0; it < 8; ++it) {
            int idx = it * 256 + tid;
            int grow = idx >> 5, gcol = idx & 31;
            float4 v = make_float4(0.f, 0.f, 0.f, 0.f);
            if (rowBase + grow < N) v = gp[idx];
            *(float4*)(As + grow * LDA0 + gcol * 4) = v;
        }
    }
    __syncthreads();

    f32x4 acc[2][4];
#pragma unroll
    for (int mt = 0; mt < 2; ++mt)
#pragma unroll
        for (int nt = 0; nt < 4; ++nt)
            acc[mt][nt] = (f32x4){0.f, 0.f, 0.f, 0.f};

#pragma unroll
    for (int s = 0; s < 4; ++s) {
        short8 wfh[4], wfl[4];
#pragma unroll
        for (int nt = 0; nt < 4; ++nt) {
            wfh[nt] = *(const short8*)(Wf + ((((nh * 2 + 0) * 4 + s) * 4 + nt) * 512) + lane * 8);
            wfl[nt] = *(const short8*)(Wf + ((((nh * 2 + 1) * 4 + s) * 4 + nt) * 512) + lane * 8);
        }
#pragma unroll
        for (int mt = 0; mt < 2; ++mt) {
            const float* ap = As + (mh * 32 + mt * 16 + r15) * LDA0 + s * 32 + quad * 8;
            short8 ah, al;
#pragma unroll
            for (int j = 0; j < 8; ++j) {
                float v = ap[j];
                unsigned short h = f2bf(v);
                ah[j] = (short)h;
                al[j] = (short)f2bf(v - bf2f(h));
            }
#pragma unroll
            for (int nt = 0; nt < 4; ++nt) {
                acc[mt][nt] = __builtin_amdgcn_mfma_f32_16x16x32_bf16(ah, wfh[nt], acc[mt][nt], 0, 0, 0);
                acc[mt][nt] = __builtin_amdgcn_mfma_f32_16x16x32_bf16(ah, wfl[nt], acc[mt][nt], 0, 0, 0);
                acc[mt][nt] = __builtin_amdgcn_mfma_f32_16x16x32_bf16(al, wfh[nt], acc[mt][nt], 0, 0, 0);
            }
        }
    }

#pragma unroll
    for (int mt = 0; mt < 2; ++mt) {
        int rl = mh * 32 + mt * 16 + quad * 4;
#pragma unroll
        for (int reg = 0; reg < 4; ++reg) {
            int row = rowBase + rl + reg;
            if (row < N) {
                float sc = dinv[row];
#pragma unroll
                for (int nt = 0; nt < 4; ++nt)
                    hs[(size_t)row * DH + nh * 64 + nt * 16 + r15] = f2bf(acc[mt][nt][reg] * sc);
            }
        }
    }
}

// ---------------- GEMM variant P (layers 1,2): bf16 hi/lo planes, pure MFMA ----------------
// padded LDS: 64 rows x 136 ushorts per plane (row stride 272 B -> 2-way alias, free)

#define LDAP 136

__launch_bounds__(256)
__global__ void k_gemm_pl(const unsigned short* __restrict__ Xh,
                          const unsigned short* __restrict__ Xl,
                          const unsigned short* __restrict__ Wf,
                          const float* __restrict__ dinv,
                          unsigned short* __restrict__ hs, int N)
{
    __shared__ unsigned short Ah[64 * LDAP];
    __shared__ unsigned short Al[64 * LDAP];

    const int tid  = threadIdx.x;
    const int lane = tid & 63, wave = tid >> 6;
    const int mh = wave >> 1, nh = wave & 1;
    const int rowBase = blockIdx.x * 64;
    const int r15 = lane & 15, quad = lane >> 4;

    {
        const uint4* gh = (const uint4*)(Xh + (size_t)rowBase * DH);
        const uint4* gl = (const uint4*)(Xl + (size_t)rowBase * DH);
#pragma unroll
        for (int it = 0; it < 4; ++it) {
            int idx = it * 256 + tid;                 // 1024 uint4 per plane
            int grow = idx >> 4, gcol8 = (idx & 15) * 8;
            uint4 vh = make_uint4(0, 0, 0, 0), vl = make_uint4(0, 0, 0, 0);
            if (rowBase + grow < N) { vh = gh[idx]; vl = gl[idx]; }
            *(uint4*)(Ah + grow * LDAP + gcol8) = vh;
            *(uint4*)(Al + grow * LDAP + gcol8) = vl;
        }
    }
    __syncthreads();

    f32x4 acc[2][4];
#pragma unroll
    for (int mt = 0; mt < 2; ++mt)
#pragma unroll
        for (int nt = 0; nt < 4; ++nt)
            acc[mt][nt] = (f32x4){0.f, 0.f, 0.f, 0.f};

#pragma unroll
    for (int s = 0; s < 4; ++s) {
        short8 wfh[4], wfl[4];
#pragma unroll
        for (int nt = 0; nt < 4; ++nt) {
            wfh[nt] = *(const short8*)(Wf + ((((nh * 2 + 0) * 4 + s) * 4 + nt) * 512) + lane * 8);
            wfl[nt] = *(const short8*)(Wf + ((((nh * 2 + 1) * 4 + s) * 4 + nt) * 512) + lane * 8);
        }
#pragma unroll
        for (int mt = 0; mt < 2; ++mt) {
            int arow = mh * 32 + mt * 16 + r15;
            short8 ah = *(const short8*)(Ah + arow * LDAP + s * 32 + quad * 8);
            short8 al = *(const short8*)(Al + arow * LDAP + s * 32 + quad * 8);
#pragma unroll
            for (int nt = 0; nt < 4; ++nt) {
                acc[mt][nt] = __builtin_amdgcn_mfma_f32_16x16x32_bf16(ah, wfh[nt], acc[mt][nt], 0, 0, 0);
                acc[mt][nt] = __builtin_amdgcn_mfma_f32_16x16x32_bf16(ah, wfl[nt], acc[mt][nt], 0, 0, 0);
                acc[mt][nt] = __builtin_amdgcn_mfma_f32_16x16x32_bf16(al, wfh[nt], acc[mt][nt], 0, 0, 0);
            }
        }
    }

#pragma unroll
    for (int mt = 0; mt < 2; ++mt) {
        int rl = mh * 32 + mt * 16 + quad * 4;
#pragma unroll
        for (int reg = 0; reg < 4; ++reg) {
            int row = rowBase + rl + reg;
            if (row < N) {
                float sc = dinv[row];
#pragma unroll
                for (int nt = 0; nt < 4; ++nt)
                    hs[(size_t)row * DH + nh * 64 + nt * 16 + r15] = f2bf(acc[mt][nt][reg] * sc);
            }
        }
    }
}

// ---------------- gather: 2 nodes/wave, writes bf16 hi/lo planes ----------------

__launch_bounds__(256)
__global__ void k_gather(const unsigned short* __restrict__ hs, const int* __restrict__ rowptr,
                         const int* __restrict__ csr_src, const float* __restrict__ dinv,
                         const float* __restrict__ cb, const float* __restrict__ bm,
                         const float* __restrict__ bv, const float* __restrict__ bg,
                         const float* __restrict__ bb,
                         const unsigned short* __restrict__ ph,   // prev hi plane (or null)
                         const unsigned short* __restrict__ pl,   // prev lo plane
                         unsigned short* __restrict__ oh,         // out hi plane
                         unsigned short* __restrict__ ol,         // out lo plane
                         int N)
{
    const int node = (blockIdx.x * blockDim.x + threadIdx.x) >> 5;
    const int lh = threadIdx.x & 31;
    if (node >= N) return;
    const int f = lh * 4;
    const int e0 = rowptr[node], e1 = rowptr[node + 1];

    ushort4 su = *(const ushort4*)(hs + (size_t)node * DH + f);      // self-loop
    float a0 = bf2f(su.x), a1 = bf2f(su.y), a2 = bf2f(su.z), a3 = bf2f(su.w);

    for (int base = e0; base < e1; base += 32) {
        int cnt = e1 - base; if (cnt > 32) cnt = 32;
        int idx = (lh < cnt) ? csr_src[base + lh] : 0;
        int i = 0;
        for (; i + 4 <= cnt; i += 4) {
            int s0 = __shfl(idx, i,     32), s1 = __shfl(idx, i + 1, 32);
            int s2 = __shfl(idx, i + 2, 32), s3 = __shfl(idx, i + 3, 32);
            ushort4 v0 = *(const ushort4*)(hs + (size_t)s0 * DH + f);
            ushort4 v1 = *(const ushort4*)(hs + (size_t)s1 * DH + f);
            ushort4 v2 = *(const ushort4*)(hs + (size_t)s2 * DH + f);
            ushort4 v3 = *(const ushort4*)(hs + (size_t)s3 * DH + f);
            a0 += (bf2f(v0.x) + bf2f(v1.x)) + (bf2f(v2.x) + bf2f(v3.x));
            a1 += (bf2f(v0.y) + bf2f(v1.y)) + (bf2f(v2.y) + bf2f(v3.y));
            a2 += (bf2f(v0.z) + bf2f(v1.z)) + (bf2f(v2.z) + bf2f(v3.z));
            a3 += (bf2f(v0.w) + bf2f(v1.w)) + (bf2f(v2.w) + bf2f(v3.w));
        }
        for (; i < cnt; ++i) {
            int s = __shfl(idx, i, 32);
            ushort4 v = *(const ushort4*)(hs + (size_t)s * DH + f);
            a0 += bf2f(v.x); a1 += bf2f(v.y); a2 += bf2f(v.z); a3 += bf2f(v.w);
        }
    }

    const float sc = dinv[node];
    const float4 vcb = *(const float4*)(cb + f);
    const float4 vbm = *(const float4*)(bm + f);
    const float4 vbv = *(const float4*)(bv + f);
    const float4 vbg = *(const float4*)(bg + f);
    const float4 vbb = *(const float4*)(bb + f);
    float o0 = (a0 * sc + vcb.x - vbm.x) * rsqrtf(vbv.x + EPSB) * vbg.x + vbb.x;
    float o1 = (a1 * sc + vcb.y - vbm.y) * rsqrtf(vbv.y + EPSB) * vbg.y + vbb.y;
    float o2 = (a2 * sc + vcb.z - vbm.z) * rsqrtf(vbv.z + EPSB) * vbg.z + vbb.z;
    float o3 = (a3 * sc + vcb.w - vbm.w) * rsqrtf(vbv.w + EPSB) * vbg.w + vbb.w;
    o0 = fmaxf(o0, 0.f); o1 = fmaxf(o1, 0.f); o2 = fmaxf(o2, 0.f); o3 = fmaxf(o3, 0.f);
    if (ph) {   // residual: prev = hi + lo (reconstruction err ~2^-18)
        ushort4 hv = *(const ushort4*)(ph + (size_t)node * DH + f);
        ushort4 lv = *(const ushort4*)(pl + (size_t)node * DH + f);
        o0 += bf2f(hv.x) + bf2f(lv.x);
        o1 += bf2f(hv.y) + bf2f(lv.y);
        o2 += bf2f(hv.z) + bf2f(lv.z);
        o3 += bf2f(hv.w) + bf2f(lv.w);
    }
    unsigned short h0 = f2bf(o0), h1 = f2bf(o1), h2 = f2bf(o2), h3 = f2bf(o3);
    *(ushort4*)(oh + (size_t)node * DH + f) = make_ushort4(h0, h1, h2, h3);
    *(ushort4*)(ol + (size_t)node * DH + f) =
        make_ushort4(f2bf(o0 - bf2f(h0)), f2bf(o1 - bf2f(h1)),
                     f2bf(o2 - bf2f(h2)), f2bf(o3 - bf2f(h3)));
}

// ---------------- fused pool (mean+max) + 3-layer MLP head (plane input) ----------------
// pooling: half = t>>6 picks even/odd rows; thread (half, tc) handles feature pair
// fc = (t&63)*2 over rows s0+half, s0+half+2, ...; halves combined via LDS partials.

__launch_bounds__(128)
__global__ void k_pool_mlp(const unsigned short* __restrict__ xh,
                           const unsigned short* __restrict__ xl,
                           const int* __restrict__ starts,
                           const float* __restrict__ L1w, const float* __restrict__ L1b,
                           const float* __restrict__ L2w, const float* __restrict__ L2b,
                           const float* __restrict__ L3w, const float* __restrict__ L3b,
                           float* __restrict__ out)
{
    int g = blockIdx.x, t = threadIdx.x;
    int s0 = starts[g], s1 = starts[g + 1];
    const int half = t >> 6;          // 0 or 1
    const int tc = t & 63;
    const int fc = tc * 2;            // feature pair, 0..126

    float sA = 0.f, sB = 0.f;
    float mA = -INFINITY, mB = -INFINITY;
    for (int i = s0 + half; i < s1; i += 2) {
        unsigned hv = *(const unsigned*)(xh + (size_t)i * DH + fc);
        unsigned lv = *(const unsigned*)(xl + (size_t)i * DH + fc);
        float vA = bf2f((unsigned short)hv) + bf2f((unsigned short)lv);
        float vB = bf2f((unsigned short)(hv >> 16)) + bf2f((unsigned short)(lv >> 16));
        sA += vA; sB += vB;
        mA = fmaxf(mA, vA); mB = fmaxf(mB, vB);
    }

    __shared__ float ps[2][128];
    __shared__ float pm[2][128];
    ps[half][fc] = sA; ps[half][fc + 1] = sB;
    pm[half][fc] = mA; pm[half][fc + 1] = mB;
    __syncthreads();

    __shared__ float h[256];
    if (half == 0) {
        float inv = 1.f / (float)(s1 - s0);
        h[fc]     = (ps[0][fc]     + ps[1][fc])     * inv;
        h[fc + 1] = (ps[0][fc + 1] + ps[1][fc + 1]) * inv;
        h[128 + fc]     = fmaxf(pm[0][fc],     pm[1][fc]);
        h[128 + fc + 1] = fmaxf(pm[0][fc + 1], pm[1][fc + 1]);
    }
    __syncthreads();

    float a = L1b[t];
    for (int k = 0; k < 256; ++k) a += h[k] * L1w[k * DH + t];
    __shared__ float h1[128];
    h1[t] = fmaxf(a, 0.f);
    __syncthreads();

    __shared__ float h2[64];
    if (t < 64) {
        float a2 = L2b[t];
        for (int k = 0; k < 128; ++k) a2 += h1[k] * L2w[k * 64 + t];
        h2[t] = fmaxf(a2, 0.f);
    }
    __syncthreads();

    if (t < 64) {
        float p = h2[t] * L3w[t];
#pragma unroll
        for (int off = 32; off > 0; off >>= 1) p += __shfl_down(p, off, 64);
        if (t == 0) out[g] = p + L3b[0];
    }
}

// ---------------- launch ----------------

static inline char* align16(char* p) {
    return (char*)(((uintptr_t)p + 15) & ~(uintptr_t)15);
}

extern "C" void kernel_launch(void* const* d_in, const int* in_sizes, int n_in,
                              void* d_out, int out_size, void* d_ws, size_t ws_size,
                              hipStream_t stream)
{
    const float* x     = (const float*)d_in[0];
    const int*   ei    = (const int*)d_in[1];
    const int*   batch = (const int*)d_in[2];
    const int N = in_sizes[0] / DH;
    const int E = in_sizes[1] / 2;
    const int G = out_size;
    const int* src = ei;
    const int* dst = ei + E;

    const float* W[3]  = {(const float*)d_in[3],  (const float*)d_in[9],  (const float*)d_in[15]};
    const float* cb[3] = {(const float*)d_in[4],  (const float*)d_in[10], (const float*)d_in[16]};
    const float* bg[3] = {(const float*)d_in[5],  (const float*)d_in[11], (const float*)d_in[17]};
    const float* bt[3] = {(const float*)d_in[6],  (const float*)d_in[12], (const float*)d_in[18]};
    const float* bm[3] = {(const float*)d_in[7],  (const float*)d_in[13], (const float*)d_in[19]};
    const float* bv[3] = {(const float*)d_in[8],  (const float*)d_in[14], (const float*)d_in[20]};
    const float* L1w = (const float*)d_in[21]; const float* L1b = (const float*)d_in[22];
    const float* L2w = (const float*)d_in[23]; const float* L2b = (const float*)d_in[24];
    const float* L3w = (const float*)d_in[25]; const float* L3b = (const float*)d_in[26];

    char* wsp = (char*)d_ws;
    size_t planeB = (size_t)N * DH * sizeof(unsigned short);   // 25.6 MB
    unsigned short* HS  = (unsigned short*)wsp; wsp += planeB;
    unsigned short* AH  = (unsigned short*)wsp; wsp += planeB;
    unsigned short* AL  = (unsigned short*)wsp; wsp += planeB;
    unsigned short* BH  = (unsigned short*)wsp; wsp += planeB;
    unsigned short* BL  = (unsigned short*)wsp; wsp += planeB;
    unsigned short* Wfrag = (unsigned short*)wsp; wsp += 3 * 65536;
    float* dinv   = (float*)wsp; wsp += (size_t)N * sizeof(float);
    int*   rowptr = (int*)wsp;   wsp = align16(wsp + (size_t)(N + 1) * sizeof(int));
    int*   csr_src= (int*)wsp;   wsp += (size_t)E * sizeof(int);
    int*   starts = (int*)wsp;   wsp = align16(wsp + (size_t)(G + 1) * sizeof(int));
    int*   gcur   = (int*)wsp;   wsp = align16(wsp + (size_t)MAXB * sizeof(int));
    int*   bbase  = (int*)wsp;   wsp = align16(wsp + (size_t)MAXB * sizeof(int));
    int*   bbuf   = (int*)wsp;   wsp += (size_t)MAXB * BCAP * sizeof(int);   // 10.2 MB

    const int NB = (N + 127) >> 7;
    const int nblkA = 128;
    const int chunk = (E + nblkA - 1) / nblkA;

    hipMemsetAsync(gcur, 0, (size_t)NB * sizeof(int), stream);
    k_bucketA<<<nblkA, 256, 0, stream>>>(src, dst, gcur, bbuf, batch, starts,
                                         E, NB, chunk, N, G);
    k_bgscan <<<1, 1024, 0, stream>>>(gcur, bbase, rowptr, NB, N, E);
    k_bfinal <<<NB, 256, 0, stream>>>(gcur, bbase, bbuf, rowptr, dinv, csr_src, N);
    k_wfrag  <<<48, 256, 0, stream>>>(W[0], W[1], W[2], Wfrag);

    int gemmGrid = (N + 63) / 64;
    int gathGrid = ((size_t)N * 32 + 255) / 256;

    // L0: gemm0(x) -> HS; gather(HS, prev=null) -> planes A
    // L1: gemm_pl(A) -> HS; gather(HS, prev=A) -> planes B
    // L2: gemm_pl(B) -> HS; gather(HS, prev=B) -> planes A
    k_gemm0<<<gemmGrid, 256, 0, stream>>>(x, Wfrag, dinv, HS, N);
    k_gather<<<gathGrid, 256, 0, stream>>>(HS, rowptr, csr_src, dinv,
                                           cb[0], bm[0], bv[0], bg[0], bt[0],
                                           nullptr, nullptr, AH, AL, N);
    k_gemm_pl<<<gemmGrid, 256, 0, stream>>>(AH, AL, Wfrag + 32768, dinv, HS, N);
    k_gather<<<gathGrid, 256, 0, stream>>>(HS, rowptr, csr_src, dinv,
                                           cb[1], bm[1], bv[1], bg[1], bt[1],
                                           AH, AL, BH, BL, N);
    k_gemm_pl<<<gemmGrid, 256, 0, stream>>>(BH, BL, Wfrag + 65536, dinv, HS, N);
    k_gather<<<gathGrid, 256, 0, stream>>>(HS, rowptr, csr_src, dinv,
                                           cb[2], bm[2], bv[2], bg[2], bt[2],
                                           BH, BL, AH, AL, N);

    k_pool_mlp<<<G, 128, 0, stream>>>(AH, AL, starts, L1w, L1b, L2w, L2b, L3w, L3b,
                                      (float*)d_out);
}

// Round 8
// 507.403 us; speedup vs baseline: 1.0447x; 1.0447x over previous
//
#include <hip/hip_runtime.h>
#include <math.h>

#define DH 128
#define EPSB 1e-5f
#define MAXB 832     // max buckets (N <= 106496)
#define BCAP 3072    // bucket capacity (mean ~2046 at E/N=16)

typedef __attribute__((ext_vector_type(8))) short short8;
typedef __attribute__((ext_vector_type(4))) float f32x4;

static __device__ __forceinline__ unsigned short f2bf(float f) {
    unsigned u = __float_as_uint(f);
    u += 0x7fffu + ((u >> 16) & 1u);
    return (unsigned short)(u >> 16);
}
static __device__ __forceinline__ float bf2f(unsigned short h) {
    return __uint_as_float(((unsigned)h) << 16);
}
static __device__ __forceinline__ float blo(unsigned u) { return __uint_as_float(u << 16); }
static __device__ __forceinline__ float bhi(unsigned u) { return __uint_as_float(u & 0xFFFF0000u); }

// ---------------- bucketed CSR build (+ fused graph-boundary pass) ----------------
// pass A: partition edges into buckets of 128 dsts; packed entry (src<<7)|dlocal
// 512 blocks (2/CU): the LDS-atomic work is the cost driver — parallelize it.

__launch_bounds__(256)
__global__ void k_bucketA(const int* __restrict__ src, const int* __restrict__ dst,
                          int* __restrict__ gcur, int* __restrict__ bbuf,
                          const int* __restrict__ batch, int* __restrict__ starts,
                          int E, int NB, int chunk, int N, int G)
{
    __shared__ int cnt[MAXB];
    __shared__ int base[MAXB];
    const int t = threadIdx.x;

    // fused: graph boundaries (independent work, grid-strided)
    for (int i = blockIdx.x * 256 + t; i < N; i += gridDim.x * 256) {
        int b = batch[i];
        if (i == 0) { starts[0] = 0; starts[G] = N; }
        else if (batch[i - 1] != b) starts[b] = i;
    }

    for (int i = t; i < NB; i += 256) cnt[i] = 0;
    __syncthreads();
    const int e0 = blockIdx.x * chunk;
    const int e1 = min(E, e0 + chunk);
    for (int e = e0 + t; e < e1; e += 256)
        atomicAdd(&cnt[dst[e] >> 7], 1);
    __syncthreads();
    for (int i = t; i < NB; i += 256) {
        int c = cnt[i];
        base[i] = (c > 0) ? atomicAdd(&gcur[i], c) : 0;
        cnt[i] = 0;
    }
    __syncthreads();
    for (int e = e0 + t; e < e1; e += 256) {
        int d = dst[e];
        int b = d >> 7;
        int o = base[b] + atomicAdd(&cnt[b], 1);
        if (o < BCAP) bbuf[(size_t)b * BCAP + o] = (src[e] << 7) | (d & 127);
    }
}

// pass B: single-block exclusive scan of bucket counts -> bucket_base; rowptr[N]=E
__launch_bounds__(1024)
__global__ void k_bgscan(const int* __restrict__ gcur, int* __restrict__ bbase,
                         int* __restrict__ rowptr, int NB, int N, int E)
{
    __shared__ int s[1024];
    int t = threadIdx.x;
    int v = (t < NB) ? min(gcur[t], BCAP) : 0;
    s[t] = v;
    __syncthreads();
    for (int off = 1; off < 1024; off <<= 1) {
        int u = (t >= off) ? s[t - off] : 0;
        __syncthreads();
        s[t] += u;
        __syncthreads();
    }
    if (t < NB) bbase[t] = s[t] - v;   // exclusive
    if (t == 0) rowptr[N] = E;
}

// pass C: per-bucket: deg count, dinv, rowptr, csr scatter (bucket staged in LDS)
__launch_bounds__(256)
__global__ void k_bfinal(const int* __restrict__ gcur, const int* __restrict__ bbase,
                         const int* __restrict__ bbuf, int* __restrict__ rowptr,
                         float* __restrict__ dinv, int* __restrict__ csr_src, int N)
{
    __shared__ int ebuf[BCAP];
    __shared__ int dcnt[128];
    __shared__ int sp[128];
    const int b = blockIdx.x, t = threadIdx.x;
    const int c = min(gcur[b], BCAP);
    const int base = bbase[b];
    const int* p = bbuf + (size_t)b * BCAP;
    for (int i = t; i < c; i += 256) ebuf[i] = p[i];
    if (t < 128) dcnt[t] = 0;
    __syncthreads();
    for (int i = t; i < c; i += 256) atomicAdd(&dcnt[ebuf[i] & 127], 1);
    __syncthreads();
    if (t < 128) sp[t] = dcnt[t];
    __syncthreads();
    for (int off = 1; off < 128; off <<= 1) {
        int u = (t < 128 && t >= off) ? sp[t - off] : 0;
        __syncthreads();
        if (t < 128) sp[t] += u;
        __syncthreads();
    }
    if (t < 128) {
        sp[t] -= dcnt[t];                 // exclusive
        int d = b * 128 + t;
        if (d < N) {
            rowptr[d] = base + sp[t];
            dinv[d] = rsqrtf((float)(dcnt[t] + 1));
        }
        dcnt[t] = 0;                      // reuse as cursor
    }
    __syncthreads();
    for (int i = t; i < c; i += 256) {
        int e = ebuf[i];
        int dl = e & 127;
        int o = atomicAdd(&dcnt[dl], 1);
        csr_src[base + sp[dl] + o] = e >> 7;
    }
}

// ---------------- W fragmentize + bf16 split (all 3 layers, 48 blocks x 256) ----------------
// Frag f = ((nh*2+p)*4+s)*4+nt; lane holds B[k=s*32+quad*8+j][n=nh*64+nt*16+(lane&15)]

__global__ void k_wfrag(const float* __restrict__ W0, const float* __restrict__ W1,
                        const float* __restrict__ W2, unsigned short* __restrict__ Wf0) {
    int fid = blockIdx.x * 4 + (threadIdx.x >> 6);   // 0..191
    int lane = threadIdx.x & 63;
    int l = fid >> 6;
    int f = fid & 63;
    const float* W = (l == 0) ? W0 : (l == 1) ? W1 : W2;
    unsigned short* Wf = Wf0 + (size_t)l * 32768;
    int nt = f & 3, s = (f >> 2) & 3, p = (f >> 4) & 1, nh = f >> 5;
    int n = nh * 64 + nt * 16 + (lane & 15);
    int kbase = s * 32 + (lane >> 4) * 8;
    unsigned short o[8];
#pragma unroll
    for (int j = 0; j < 8; ++j) {
        float w = W[(size_t)(kbase + j) * DH + n];
        unsigned short h = f2bf(w);
        o[j] = p ? f2bf(w - bf2f(h)) : h;
    }
    unsigned short* d = Wf + (size_t)f * 512 + lane * 8;
    *(ushort4*)d       = make_ushort4(o[0], o[1], o[2], o[3]);
    *(ushort4*)(d + 4) = make_ushort4(o[4], o[5], o[6], o[7]);
}

// ---------------- GEMM variant 0 (layer 0): fp32 X, in-register split ----------------
// padded LDS: 64 rows x 132 floats (row stride 528 B -> 2-way bank alias, free)

#define LDA0 132

__launch_bounds__(256)
__global__ void k_gemm0(const float* __restrict__ X,
                        const unsigned short* __restrict__ Wf,
                        const float* __restrict__ dinv,
                        unsigned short* __restrict__ hs, int N)
{
    __shared__ float As[64 * LDA0];

    const int tid  = threadIdx.x;
    const int lane = tid & 63, wave = tid >> 6;
    const int mh = wave >> 1, nh = wave & 1;
    const int rowBase = blockIdx.x * 64;
    const int r15 = lane & 15, quad = lane >> 4;

    {
        const float4* gp = (const float4*)(X + (size_t)rowBase * DH);
#pragma unroll
        for (int it = 0; it < 8; ++it) {
            int idx = it * 256 + tid;
            int grow = idx >> 5, gcol = idx & 31;
            float4 v = make_float4(0.f, 0.f, 0.f, 0.f);
            if (rowBase + grow < N) v = gp[idx];
            *(float4*)(As + grow * LDA0 + gcol * 4) = v;
        }
    }
    __syncthreads();

    f32x4 acc[2][4];
#pragma unroll
    for (int mt = 0; mt < 2; ++mt)
#pragma unroll
        for (int nt = 0; nt < 4; ++nt)
            acc[mt][nt] = (f32x4){0.f, 0.f, 0.f, 0.f};

#pragma unroll
    for (int s = 0; s < 4; ++s) {
        short8 wfh[4], wfl[4];
#pragma unroll
        for (int nt = 0; nt < 4; ++nt) {
            wfh[nt] = *(const short8*)(Wf + ((((nh * 2 + 0) * 4 + s) * 4 + nt) * 512) + lane * 8);
            wfl[nt] = *(const short8*)(Wf + ((((nh * 2 + 1) * 4 + s) * 4 + nt) * 512) + lane * 8);
        }
#pragma unroll
        for (int mt = 0; mt < 2; ++mt) {
            const float* ap = As + (mh * 32 + mt * 16 + r15) * LDA0 + s * 32 + quad * 8;
            short8 ah, al;
#pragma unroll
            for (int j = 0; j < 8; ++j) {
                float v = ap[j];
                unsigned short h = f2bf(v);
                ah[j] = (short)h;
                al[j] = (short)f2bf(v - bf2f(h));
            }
#pragma unroll
            for (int nt = 0; nt < 4; ++nt) {
                acc[mt][nt] = __builtin_amdgcn_mfma_f32_16x16x32_bf16(ah, wfh[nt], acc[mt][nt], 0, 0, 0);
                acc[mt][nt] = __builtin_amdgcn_mfma_f32_16x16x32_bf16(ah, wfl[nt], acc[mt][nt], 0, 0, 0);
                acc[mt][nt] = __builtin_amdgcn_mfma_f32_16x16x32_bf16(al, wfh[nt], acc[mt][nt], 0, 0, 0);
            }
        }
    }

#pragma unroll
    for (int mt = 0; mt < 2; ++mt) {
        int rl = mh * 32 + mt * 16 + quad * 4;
#pragma unroll
        for (int reg = 0; reg < 4; ++reg) {
            int row = rowBase + rl + reg;
            if (row < N) {
                float sc = dinv[row];
#pragma unroll
                for (int nt = 0; nt < 4; ++nt)
                    hs[(size_t)row * DH + nh * 64 + nt * 16 + r15] = f2bf(acc[mt][nt][reg] * sc);
            }
        }
    }
}

// ---------------- GEMM variant P (layers 1,2): bf16 hi/lo planes, pure MFMA ----------------
// padded LDS: 64 rows x 136 ushorts per plane (row stride 272 B -> 2-way alias, free)

#define LDAP 136

__launch_bounds__(256)
__global__ void k_gemm_pl(const unsigned short* __restrict__ Xh,
                          const unsigned short* __restrict__ Xl,
                          const unsigned short* __restrict__ Wf,
                          const float* __restrict__ dinv,
                          unsigned short* __restrict__ hs, int N)
{
    __shared__ unsigned short Ah[64 * LDAP];
    __shared__ unsigned short Al[64 * LDAP];

    const int tid  = threadIdx.x;
    const int lane = tid & 63, wave = tid >> 6;
    const int mh = wave >> 1, nh = wave & 1;
    const int rowBase = blockIdx.x * 64;
    const int r15 = lane & 15, quad = lane >> 4;

    {
        const uint4* gh = (const uint4*)(Xh + (size_t)rowBase * DH);
        const uint4* gl = (const uint4*)(Xl + (size_t)rowBase * DH);
#pragma unroll
        for (int it = 0; it < 4; ++it) {
            int idx = it * 256 + tid;                 // 1024 uint4 per plane
            int grow = idx >> 4, gcol8 = (idx & 15) * 8;
            uint4 vh = make_uint4(0, 0, 0, 0), vl = make_uint4(0, 0, 0, 0);
            if (rowBase + grow < N) { vh = gh[idx]; vl = gl[idx]; }
            *(uint4*)(Ah + grow * LDAP + gcol8) = vh;
            *(uint4*)(Al + grow * LDAP + gcol8) = vl;
        }
    }
    __syncthreads();

    f32x4 acc[2][4];
#pragma unroll
    for (int mt = 0; mt < 2; ++mt)
#pragma unroll
        for (int nt = 0; nt < 4; ++nt)
            acc[mt][nt] = (f32x4){0.f, 0.f, 0.f, 0.f};

#pragma unroll
    for (int s = 0; s < 4; ++s) {
        short8 wfh[4], wfl[4];
#pragma unroll
        for (int nt = 0; nt < 4; ++nt) {
            wfh[nt] = *(const short8*)(Wf + ((((nh * 2 + 0) * 4 + s) * 4 + nt) * 512) + lane * 8);
            wfl[nt] = *(const short8*)(Wf + ((((nh * 2 + 1) * 4 + s) * 4 + nt) * 512) + lane * 8);
        }
#pragma unroll
        for (int mt = 0; mt < 2; ++mt) {
            int arow = mh * 32 + mt * 16 + r15;
            short8 ah = *(const short8*)(Ah + arow * LDAP + s * 32 + quad * 8);
            short8 al = *(const short8*)(Al + arow * LDAP + s * 32 + quad * 8);
#pragma unroll
            for (int nt = 0; nt < 4; ++nt) {
                acc[mt][nt] = __builtin_amdgcn_mfma_f32_16x16x32_bf16(ah, wfh[nt], acc[mt][nt], 0, 0, 0);
                acc[mt][nt] = __builtin_amdgcn_mfma_f32_16x16x32_bf16(ah, wfl[nt], acc[mt][nt], 0, 0, 0);
                acc[mt][nt] = __builtin_amdgcn_mfma_f32_16x16x32_bf16(al, wfh[nt], acc[mt][nt], 0, 0, 0);
            }
        }
    }

#pragma unroll
    for (int mt = 0; mt < 2; ++mt) {
        int rl = mh * 32 + mt * 16 + quad * 4;
#pragma unroll
        for (int reg = 0; reg < 4; ++reg) {
            int row = rowBase + rl + reg;
            if (row < N) {
                float sc = dinv[row];
#pragma unroll
                for (int nt = 0; nt < 4; ++nt)
                    hs[(size_t)row * DH + nh * 64 + nt * 16 + r15] = f2bf(acc[mt][nt][reg] * sc);
            }
        }
    }
}

// ---------------- gather v3: 4 nodes/wave (16 lanes each, uint4 = 16 B loads) ----------------

__launch_bounds__(256)
__global__ void k_gather(const unsigned short* __restrict__ hs, const int* __restrict__ rowptr,
                         const int* __restrict__ csr_src, const float* __restrict__ dinv,
                         const float* __restrict__ cb, const float* __restrict__ bm,
                         const float* __restrict__ bv, const float* __restrict__ bg,
                         const float* __restrict__ bb,
                         const unsigned short* __restrict__ ph,   // prev hi plane (or null)
                         const unsigned short* __restrict__ pl,   // prev lo plane
                         unsigned short* __restrict__ oh,         // out hi plane
                         unsigned short* __restrict__ ol,         // out lo plane
                         int N)
{
    const int node = (blockIdx.x * blockDim.x + threadIdx.x) >> 4;
    const int lh = threadIdx.x & 15;
    if (node >= N) return;
    const int f = lh * 8;                           // 8 features per lane
    const int e0 = rowptr[node], e1 = rowptr[node + 1];

    const uint4* hsv = (const uint4*)hs;            // row = 16 uint4
    float a[8];
    {
        uint4 sv = hsv[(size_t)node * 16 + lh];     // self-loop
        a[0] = blo(sv.x); a[1] = bhi(sv.x); a[2] = blo(sv.y); a[3] = bhi(sv.y);
        a[4] = blo(sv.z); a[5] = bhi(sv.z); a[6] = blo(sv.w); a[7] = bhi(sv.w);
    }

    for (int base = e0; base < e1; base += 16) {
        int cnt = e1 - base; if (cnt > 16) cnt = 16;
        int idx = (lh < cnt) ? csr_src[base + lh] : 0;
        int i = 0;
        for (; i + 4 <= cnt; i += 4) {
            int s0 = __shfl(idx, i,     16), s1 = __shfl(idx, i + 1, 16);
            int s2 = __shfl(idx, i + 2, 16), s3 = __shfl(idx, i + 3, 16);
            uint4 v0 = hsv[(size_t)s0 * 16 + lh];
            uint4 v1 = hsv[(size_t)s1 * 16 + lh];
            uint4 v2 = hsv[(size_t)s2 * 16 + lh];
            uint4 v3 = hsv[(size_t)s3 * 16 + lh];
            a[0] += (blo(v0.x) + blo(v1.x)) + (blo(v2.x) + blo(v3.x));
            a[1] += (bhi(v0.x) + bhi(v1.x)) + (bhi(v2.x) + bhi(v3.x));
            a[2] += (blo(v0.y) + blo(v1.y)) + (blo(v2.y) + blo(v3.y));
            a[3] += (bhi(v0.y) + bhi(v1.y)) + (bhi(v2.y) + bhi(v3.y));
            a[4] += (blo(v0.z) + blo(v1.z)) + (blo(v2.z) + blo(v3.z));
            a[5] += (bhi(v0.z) + bhi(v1.z)) + (bhi(v2.z) + bhi(v3.z));
            a[6] += (blo(v0.w) + blo(v1.w)) + (blo(v2.w) + blo(v3.w));
            a[7] += (bhi(v0.w) + bhi(v1.w)) + (bhi(v2.w) + bhi(v3.w));
        }
        for (; i < cnt; ++i) {
            int s = __shfl(idx, i, 16);
            uint4 v = hsv[(size_t)s * 16 + lh];
            a[0] += blo(v.x); a[1] += bhi(v.x); a[2] += blo(v.y); a[3] += bhi(v.y);
            a[4] += blo(v.z); a[5] += bhi(v.z); a[6] += blo(v.w); a[7] += bhi(v.w);
        }
    }

    const float sc = dinv[node];
    float cbv[8], bmv[8], bvv[8], bgv[8], bbv[8];
    *(float4*)cbv = *(const float4*)(cb + f); *(float4*)(cbv + 4) = *(const float4*)(cb + f + 4);
    *(float4*)bmv = *(const float4*)(bm + f); *(float4*)(bmv + 4) = *(const float4*)(bm + f + 4);
    *(float4*)bvv = *(const float4*)(bv + f); *(float4*)(bvv + 4) = *(const float4*)(bv + f + 4);
    *(float4*)bgv = *(const float4*)(bg + f); *(float4*)(bgv + 4) = *(const float4*)(bg + f + 4);
    *(float4*)bbv = *(const float4*)(bb + f); *(float4*)(bbv + 4) = *(const float4*)(bb + f + 4);

    float o[8];
#pragma unroll
    for (int j = 0; j < 8; ++j) {
        float v = (a[j] * sc + cbv[j] - bmv[j]) * rsqrtf(bvv[j] + EPSB) * bgv[j] + bbv[j];
        o[j] = fmaxf(v, 0.f);
    }
    if (ph) {   // residual: prev = hi + lo (reconstruction err ~2^-18)
        uint4 hv = *(const uint4*)(ph + (size_t)node * DH + f);
        uint4 lv = *(const uint4*)(pl + (size_t)node * DH + f);
        o[0] += blo(hv.x) + blo(lv.x); o[1] += bhi(hv.x) + bhi(lv.x);
        o[2] += blo(hv.y) + blo(lv.y); o[3] += bhi(hv.y) + bhi(lv.y);
        o[4] += blo(hv.z) + blo(lv.z); o[5] += bhi(hv.z) + bhi(lv.z);
        o[6] += blo(hv.w) + blo(lv.w); o[7] += bhi(hv.w) + bhi(lv.w);
    }
    unsigned hw[4], lw[4];
#pragma unroll
    for (int p = 0; p < 4; ++p) {
        unsigned short hA = f2bf(o[2 * p]), hB = f2bf(o[2 * p + 1]);
        hw[p] = (unsigned)hA | ((unsigned)hB << 16);
        lw[p] = (unsigned)f2bf(o[2 * p] - bf2f(hA)) |
                ((unsigned)f2bf(o[2 * p + 1] - bf2f(hB)) << 16);
    }
    *(uint4*)(oh + (size_t)node * DH + f) = make_uint4(hw[0], hw[1], hw[2], hw[3]);
    *(uint4*)(ol + (size_t)node * DH + f) = make_uint4(lw[0], lw[1], lw[2], lw[3]);
}

// ---------------- fused pool (mean+max) + 3-layer MLP head (plane input) ----------------
// pooling: 256 threads = 4 row-groups x 64 feature-pairs; rg = t>>6 strides rows by 4;
// fc = (t&63)*2 in [0,126]; partials combined via LDS.

__launch_bounds__(256)
__global__ void k_pool_mlp(const unsigned short* __restrict__ xh,
                           const unsigned short* __restrict__ xl,
                           const int* __restrict__ starts,
                           const float* __restrict__ L1w, const float* __restrict__ L1b,
                           const float* __restrict__ L2w, const float* __restrict__ L2b,
                           const float* __restrict__ L3w, const float* __restrict__ L3b,
                           float* __restrict__ out)
{
    int g = blockIdx.x, t = threadIdx.x;
    int s0 = starts[g], s1 = starts[g + 1];
    const int rg = t >> 6;            // 0..3
    const int tc = t & 63;
    const int fc = tc * 2;            // 0..126

    float sA = 0.f, sB = 0.f;
    float mA = -INFINITY, mB = -INFINITY;
    for (int i = s0 + rg; i < s1; i += 4) {
        unsigned hv = *(const unsigned*)(xh + (size_t)i * DH + fc);
        unsigned lv = *(const unsigned*)(xl + (size_t)i * DH + fc);
        float vA = blo(hv) + blo(lv);
        float vB = bhi(hv) + bhi(lv);
        sA += vA; sB += vB;
        mA = fmaxf(mA, vA); mB = fmaxf(mB, vB);
    }

    __shared__ float ps[4][128];
    __shared__ float pm[4][128];
    ps[rg][fc] = sA; ps[rg][fc + 1] = sB;
    pm[rg][fc] = mA; pm[rg][fc + 1] = mB;
    __syncthreads();

    __shared__ float h[256];
    if (rg == 0) {     // threads 0..63 finalize both features of their pair
        float inv = 1.f / (float)(s1 - s0);
#pragma unroll
        for (int j = 0; j < 2; ++j) {
            int fi = fc + j;
            h[fi] = ((ps[0][fi] + ps[1][fi]) + (ps[2][fi] + ps[3][fi])) * inv;
            h[128 + fi] = fmaxf(fmaxf(pm[0][fi], pm[1][fi]), fmaxf(pm[2][fi], pm[3][fi]));
        }
    }
    __syncthreads();

    __shared__ float h1[128];
    if (t < 128) {
        float a = L1b[t];
        for (int k = 0; k < 256; ++k) a += h[k] * L1w[k * DH + t];
        h1[t] = fmaxf(a, 0.f);
    }
    __syncthreads();

    __shared__ float h2[64];
    if (t < 64) {
        float a2 = L2b[t];
        for (int k = 0; k < 128; ++k) a2 += h1[k] * L2w[k * 64 + t];
        h2[t] = fmaxf(a2, 0.f);
    }
    __syncthreads();

    if (t < 64) {
        float p = h2[t] * L3w[t];
#pragma unroll
        for (int off = 32; off > 0; off >>= 1) p += __shfl_down(p, off, 64);
        if (t == 0) out[g] = p + L3b[0];
    }
}

// ---------------- launch ----------------

static inline char* align16(char* p) {
    return (char*)(((uintptr_t)p + 15) & ~(uintptr_t)15);
}

extern "C" void kernel_launch(void* const* d_in, const int* in_sizes, int n_in,
                              void* d_out, int out_size, void* d_ws, size_t ws_size,
                              hipStream_t stream)
{
    const float* x     = (const float*)d_in[0];
    const int*   ei    = (const int*)d_in[1];
    const int*   batch = (const int*)d_in[2];
    const int N = in_sizes[0] / DH;
    const int E = in_sizes[1] / 2;
    const int G = out_size;
    const int* src = ei;
    const int* dst = ei + E;

    const float* W[3]  = {(const float*)d_in[3],  (const float*)d_in[9],  (const float*)d_in[15]};
    const float* cb[3] = {(const float*)d_in[4],  (const float*)d_in[10], (const float*)d_in[16]};
    const float* bg[3] = {(const float*)d_in[5],  (const float*)d_in[11], (const float*)d_in[17]};
    const float* bt[3] = {(const float*)d_in[6],  (const float*)d_in[12], (const float*)d_in[18]};
    const float* bm[3] = {(const float*)d_in[7],  (const float*)d_in[13], (const float*)d_in[19]};
    const float* bv[3] = {(const float*)d_in[8],  (const float*)d_in[14], (const float*)d_in[20]};
    const float* L1w = (const float*)d_in[21]; const float* L1b = (const float*)d_in[22];
    const float* L2w = (const float*)d_in[23]; const float* L2b = (const float*)d_in[24];
    const float* L3w = (const float*)d_in[25]; const float* L3b = (const float*)d_in[26];

    char* wsp = (char*)d_ws;
    size_t planeB = (size_t)N * DH * sizeof(unsigned short);   // 25.6 MB
    unsigned short* HS  = (unsigned short*)wsp; wsp += planeB;
    unsigned short* AH  = (unsigned short*)wsp; wsp += planeB;
    unsigned short* AL  = (unsigned short*)wsp; wsp += planeB;
    unsigned short* BH  = (unsigned short*)wsp; wsp += planeB;
    unsigned short* BL  = (unsigned short*)wsp; wsp += planeB;
    unsigned short* Wfrag = (unsigned short*)wsp; wsp += 3 * 65536;
    float* dinv   = (float*)wsp; wsp += (size_t)N * sizeof(float);
    int*   rowptr = (int*)wsp;   wsp = align16(wsp + (size_t)(N + 1) * sizeof(int));
    int*   csr_src= (int*)wsp;   wsp += (size_t)E * sizeof(int);
    int*   starts = (int*)wsp;   wsp = align16(wsp + (size_t)(G + 1) * sizeof(int));
    int*   gcur   = (int*)wsp;   wsp = align16(wsp + (size_t)MAXB * sizeof(int));
    int*   bbase  = (int*)wsp;   wsp = align16(wsp + (size_t)MAXB * sizeof(int));
    int*   bbuf   = (int*)wsp;   wsp += (size_t)MAXB * BCAP * sizeof(int);   // 10.2 MB

    const int NB = (N + 127) >> 7;
    const int nblkA = 512;                      // 2 blocks/CU — the LDS-atomic work scales down
    const int chunk = (E + nblkA - 1) / nblkA;

    hipMemsetAsync(gcur, 0, (size_t)NB * sizeof(int), stream);
    k_bucketA<<<nblkA, 256, 0, stream>>>(src, dst, gcur, bbuf, batch, starts,
                                         E, NB, chunk, N, G);
    k_bgscan <<<1, 1024, 0, stream>>>(gcur, bbase, rowptr, NB, N, E);
    k_bfinal <<<NB, 256, 0, stream>>>(gcur, bbase, bbuf, rowptr, dinv, csr_src, N);
    k_wfrag  <<<48, 256, 0, stream>>>(W[0], W[1], W[2], Wfrag);

    int gemmGrid = (N + 63) / 64;
    int gathGrid = ((size_t)N * 16 + 255) / 256;

    // L0: gemm0(x) -> HS; gather(HS, prev=null) -> planes A
    // L1: gemm_pl(A) -> HS; gather(HS, prev=A) -> planes B
    // L2: gemm_pl(B) -> HS; gather(HS, prev=B) -> planes A
    k_gemm0<<<gemmGrid, 256, 0, stream>>>(x, Wfrag, dinv, HS, N);
    k_gather<<<gathGrid, 256, 0, stream>>>(HS, rowptr, csr_src, dinv,
                                           cb[0], bm[0], bv[0], bg[0], bt[0],
                                           nullptr, nullptr, AH, AL, N);
    k_gemm_pl<<<gemmGrid, 256, 0, stream>>>(AH, AL, Wfrag + 32768, dinv, HS, N);
    k_gather<<<gathGrid, 256, 0, stream>>>(HS, rowptr, csr_src, dinv,
                                           cb[1], bm[1], bv[1], bg[1], bt[1],
                                           AH, AL, BH, BL, N);
    k_gemm_pl<<<gemmGrid, 256, 0, stream>>>(BH, BL, Wfrag + 65536, dinv, HS, N);
    k_gather<<<gathGrid, 256, 0, stream>>>(HS, rowptr, csr_src, dinv,
                                           cb[2], bm[2], bv[2], bg[2], bt[2],
                                           BH, BL, AH, AL, N);

    k_pool_mlp<<<G, 256, 0, stream>>>(AH, AL, starts, L1w, L1b, L2w, L2b, L3w, L3b,
                                      (float*)d_out);
}

// Round 9
// 486.664 us; speedup vs baseline: 1.0892x; 1.0426x over previous
//
#include <hip/hip_runtime.h>
#include <math.h>

#define DH 128
#define EPSB 1e-5f
#define MAXB 832     // max buckets (N <= 106496)
#define BCAP 2560    // bucket capacity (mean ~2046 at E/N=16, +11 sigma)
#define LDAP 136     // padded LDS row stride (ushorts)

typedef __attribute__((ext_vector_type(8))) short short8;
typedef __attribute__((ext_vector_type(4))) float f32x4;

static __device__ __forceinline__ unsigned short f2bf(float f) {
    unsigned u = __float_as_uint(f);
    u += 0x7fffu + ((u >> 16) & 1u);
    return (unsigned short)(u >> 16);
}
static __device__ __forceinline__ float bf2f(unsigned short h) {
    return __uint_as_float(((unsigned)h) << 16);
}
static __device__ __forceinline__ float blo(unsigned u) { return __uint_as_float(u << 16); }
static __device__ __forceinline__ float bhi(unsigned u) { return __uint_as_float(u & 0xFFFF0000u); }

// ---------------- pass A: edge bucketing + graph bounds + W fragmentize ----------------
// blocks 0..511: partition edges into buckets of 128 dsts at FIXED base b*BCAP
// blocks 512..559: W fragmentize (3 layers x 64 frags)

__launch_bounds__(256)
__global__ void k_bucketA(const int* __restrict__ src, const int* __restrict__ dst,
                          int* __restrict__ gcur, int* __restrict__ bbuf,
                          const int* __restrict__ batch, int* __restrict__ starts,
                          const float* __restrict__ W0, const float* __restrict__ W1,
                          const float* __restrict__ W2, unsigned short* __restrict__ Wf0,
                          int E, int NB, int chunk, int N, int G)
{
    const int t = threadIdx.x;

    if (blockIdx.x >= 512) {            // ---- W fragmentize ----
        int fid = (blockIdx.x - 512) * 4 + (t >> 6);   // 0..191
        int lane = t & 63;
        int l = fid >> 6, f = fid & 63;
        const float* W = (l == 0) ? W0 : (l == 1) ? W1 : W2;
        unsigned short* Wf = Wf0 + (size_t)l * 32768;
        int nt = f & 3, s = (f >> 2) & 3, p = (f >> 4) & 1, nh = f >> 5;
        int n = nh * 64 + nt * 16 + (lane & 15);
        int kbase = s * 32 + (lane >> 4) * 8;
        unsigned short o[8];
#pragma unroll
        for (int j = 0; j < 8; ++j) {
            float w = W[(size_t)(kbase + j) * DH + n];
            unsigned short h = f2bf(w);
            o[j] = p ? f2bf(w - bf2f(h)) : h;
        }
        unsigned short* d = Wf + (size_t)f * 512 + lane * 8;
        *(ushort4*)d       = make_ushort4(o[0], o[1], o[2], o[3]);
        *(ushort4*)(d + 4) = make_ushort4(o[4], o[5], o[6], o[7]);
        return;
    }

    __shared__ int cnt[MAXB];
    __shared__ int base[MAXB];

    // fused: graph boundaries
    for (int i = blockIdx.x * 256 + t; i < N; i += 512 * 256) {
        int b = batch[i];
        if (i == 0) { starts[0] = 0; starts[G] = N; }
        else if (batch[i - 1] != b) starts[b] = i;
    }

    for (int i = t; i < NB; i += 256) cnt[i] = 0;
    __syncthreads();
    const int e0 = blockIdx.x * chunk;
    const int e1 = min(E, e0 + chunk);
    for (int e = e0 + t; e < e1; e += 256)
        atomicAdd(&cnt[dst[e] >> 7], 1);
    __syncthreads();
    for (int i = t; i < NB; i += 256) {
        int c = cnt[i];
        base[i] = (c > 0) ? atomicAdd(&gcur[i], c) : 0;
        cnt[i] = 0;
    }
    __syncthreads();
    for (int e = e0 + t; e < e1; e += 256) {
        int d = dst[e];
        int b = d >> 7;
        int o = base[b] + atomicAdd(&cnt[b], 1);
        if (o < BCAP) bbuf[(size_t)b * BCAP + o] = (src[e] << 7) | (d & 127);
    }
}

// ---------------- pass B: per-bucket deg/dinv/rowinfo + in-place csr scatter ----------------
// fixed bucket base b*BCAP; csr written back into bbuf (staged through LDS first)

__launch_bounds__(256)
__global__ void k_bfinal(const int* __restrict__ gcur, int* __restrict__ bbuf,
                         int2* __restrict__ rowinfo, float* __restrict__ dinv, int N)
{
    __shared__ int ebuf[BCAP];
    __shared__ int dcnt[128];
    __shared__ int sp[128];
    const int b = blockIdx.x, t = threadIdx.x;
    const int c = min(gcur[b], BCAP);
    const int base = b * BCAP;
    int* p = bbuf + base;
    for (int i = t; i < c; i += 256) ebuf[i] = p[i];
    if (t < 128) dcnt[t] = 0;
    __syncthreads();
    for (int i = t; i < c; i += 256) atomicAdd(&dcnt[ebuf[i] & 127], 1);
    __syncthreads();
    if (t < 128) sp[t] = dcnt[t];
    __syncthreads();
    for (int off = 1; off < 128; off <<= 1) {
        int u = (t < 128 && t >= off) ? sp[t - off] : 0;
        __syncthreads();
        if (t < 128) sp[t] += u;
        __syncthreads();
    }
    if (t < 128) {
        sp[t] -= dcnt[t];                 // exclusive
        int d = b * 128 + t;
        if (d < N) {
            rowinfo[d] = make_int2(base + sp[t], base + sp[t] + dcnt[t]);
            dinv[d] = rsqrtf((float)(dcnt[t] + 1));
        }
        dcnt[t] = 0;                      // reuse as cursor
    }
    __syncthreads();
    for (int i = t; i < c; i += 256) {
        int e = ebuf[i];
        int dl = e & 127;
        int o = atomicAdd(&dcnt[dl], 1);
        p[sp[dl] + o] = e >> 7;           // in-place: csr = bbuf
    }
}

// ---------------- GEMM layer 0: fp32 X, in-register bf16x3 split ----------------

#define LDA0 132

__launch_bounds__(256)
__global__ void k_gemm0(const float* __restrict__ X,
                        const unsigned short* __restrict__ Wf,
                        const float* __restrict__ dinv,
                        unsigned short* __restrict__ hs, int N)
{
    __shared__ float As[64 * LDA0];

    const int tid  = threadIdx.x;
    const int lane = tid & 63, wave = tid >> 6;
    const int mh = wave >> 1, nh = wave & 1;
    const int rowBase = blockIdx.x * 64;
    const int r15 = lane & 15, quad = lane >> 4;

    {
        const float4* gp = (const float4*)(X + (size_t)rowBase * DH);
#pragma unroll
        for (int it = 0; it < 8; ++it) {
            int idx = it * 256 + tid;
            int grow = idx >> 5, gcol = idx & 31;
            float4 v = make_float4(0.f, 0.f, 0.f, 0.f);
            if (rowBase + grow < N) v = gp[idx];
            *(float4*)(As + grow * LDA0 + gcol * 4) = v;
        }
    }
    __syncthreads();

    f32x4 acc[2][4];
#pragma unroll
    for (int mt = 0; mt < 2; ++mt)
#pragma unroll
        for (int nt = 0; nt < 4; ++nt)
            acc[mt][nt] = (f32x4){0.f, 0.f, 0.f, 0.f};

#pragma unroll
    for (int s = 0; s < 4; ++s) {
        short8 wfh[4], wfl[4];
#pragma unroll
        for (int nt = 0; nt < 4; ++nt) {
            wfh[nt] = *(const short8*)(Wf + ((((nh * 2 + 0) * 4 + s) * 4 + nt) * 512) + lane * 8);
            wfl[nt] = *(const short8*)(Wf + ((((nh * 2 + 1) * 4 + s) * 4 + nt) * 512) + lane * 8);
        }
#pragma unroll
        for (int mt = 0; mt < 2; ++mt) {
            const float* ap = As + (mh * 32 + mt * 16 + r15) * LDA0 + s * 32 + quad * 8;
            short8 ah, al;
#pragma unroll
            for (int j = 0; j < 8; ++j) {
                float v = ap[j];
                unsigned short h = f2bf(v);
                ah[j] = (short)h;
                al[j] = (short)f2bf(v - bf2f(h));
            }
#pragma unroll
            for (int nt = 0; nt < 4; ++nt) {
                acc[mt][nt] = __builtin_amdgcn_mfma_f32_16x16x32_bf16(ah, wfh[nt], acc[mt][nt], 0, 0, 0);
                acc[mt][nt] = __builtin_amdgcn_mfma_f32_16x16x32_bf16(ah, wfl[nt], acc[mt][nt], 0, 0, 0);
                acc[mt][nt] = __builtin_amdgcn_mfma_f32_16x16x32_bf16(al, wfh[nt], acc[mt][nt], 0, 0, 0);
            }
        }
    }

#pragma unroll
    for (int mt = 0; mt < 2; ++mt) {
        int rl = mh * 32 + mt * 16 + quad * 4;
#pragma unroll
        for (int reg = 0; reg < 4; ++reg) {
            int row = rowBase + rl + reg;
            if (row < N) {
                float sc = dinv[row];
#pragma unroll
                for (int nt = 0; nt < 4; ++nt)
                    hs[(size_t)row * DH + nh * 64 + nt * 16 + r15] = f2bf(acc[mt][nt][reg] * sc);
            }
        }
    }
}

// ---------------- fused gather + post + next-layer MFMA GEMM ----------------
// block = 256 thr = 16 nodes x 16 lanes. After gather+BN+ReLU+residual, the block's
// 16 feature rows go to LDS (bf16 hi/lo) and 4 waves compute hs_next = dinv*(feat@W)
// via 24 MFMA each (wave w owns output cols w*32..w*32+32).

__launch_bounds__(256)
__global__ void k_gather_mm(const unsigned short* __restrict__ hs,
                            const int2* __restrict__ rowinfo,
                            const int* __restrict__ csr_src,
                            const float* __restrict__ dinv,
                            const float* __restrict__ cb, const float* __restrict__ bm,
                            const float* __restrict__ bv, const float* __restrict__ bg,
                            const float* __restrict__ bb,
                            const float* __restrict__ prev,     // fp32 residual or null
                            float* __restrict__ feat,           // fp32 features out
                            const unsigned short* __restrict__ Wf,
                            unsigned short* __restrict__ hs_next,
                            int N)
{
    __shared__ unsigned short Ah[16 * LDAP];
    __shared__ unsigned short Al[16 * LDAP];

    const int tid = threadIdx.x;
    const int nb = tid >> 4, lh = tid & 15;
    const int nodeBase = blockIdx.x * 16;
    const int node = nodeBase + nb;
    const int f = lh * 8;

    if (node < N) {
        int2 ri = rowinfo[node];
        const uint4* hsv = (const uint4*)hs;
        float a[8];
        {
            uint4 sv = hsv[(size_t)node * 16 + lh];   // self-loop
            a[0] = blo(sv.x); a[1] = bhi(sv.x); a[2] = blo(sv.y); a[3] = bhi(sv.y);
            a[4] = blo(sv.z); a[5] = bhi(sv.z); a[6] = blo(sv.w); a[7] = bhi(sv.w);
        }
        for (int base = ri.x; base < ri.y; base += 16) {
            int cnt = ri.y - base; if (cnt > 16) cnt = 16;
            int idx = (lh < cnt) ? csr_src[base + lh] : 0;
            int i = 0;
            for (; i + 4 <= cnt; i += 4) {
                int s0 = __shfl(idx, i,     16), s1 = __shfl(idx, i + 1, 16);
                int s2 = __shfl(idx, i + 2, 16), s3 = __shfl(idx, i + 3, 16);
                uint4 v0 = hsv[(size_t)s0 * 16 + lh];
                uint4 v1 = hsv[(size_t)s1 * 16 + lh];
                uint4 v2 = hsv[(size_t)s2 * 16 + lh];
                uint4 v3 = hsv[(size_t)s3 * 16 + lh];
                a[0] += (blo(v0.x) + blo(v1.x)) + (blo(v2.x) + blo(v3.x));
                a[1] += (bhi(v0.x) + bhi(v1.x)) + (bhi(v2.x) + bhi(v3.x));
                a[2] += (blo(v0.y) + blo(v1.y)) + (blo(v2.y) + blo(v3.y));
                a[3] += (bhi(v0.y) + bhi(v1.y)) + (bhi(v2.y) + bhi(v3.y));
                a[4] += (blo(v0.z) + blo(v1.z)) + (blo(v2.z) + blo(v3.z));
                a[5] += (bhi(v0.z) + bhi(v1.z)) + (bhi(v2.z) + bhi(v3.z));
                a[6] += (blo(v0.w) + blo(v1.w)) + (blo(v2.w) + blo(v3.w));
                a[7] += (bhi(v0.w) + bhi(v1.w)) + (bhi(v2.w) + bhi(v3.w));
            }
            for (; i < cnt; ++i) {
                int s = __shfl(idx, i, 16);
                uint4 v = hsv[(size_t)s * 16 + lh];
                a[0] += blo(v.x); a[1] += bhi(v.x); a[2] += blo(v.y); a[3] += bhi(v.y);
                a[4] += blo(v.z); a[5] += bhi(v.z); a[6] += blo(v.w); a[7] += bhi(v.w);
            }
        }

        const float sc = dinv[node];
        float cbv[8], bmv[8], bvv[8], bgv[8], bbv[8];
        *(float4*)cbv = *(const float4*)(cb + f); *(float4*)(cbv + 4) = *(const float4*)(cb + f + 4);
        *(float4*)bmv = *(const float4*)(bm + f); *(float4*)(bmv + 4) = *(const float4*)(bm + f + 4);
        *(float4*)bvv = *(const float4*)(bv + f); *(float4*)(bvv + 4) = *(const float4*)(bv + f + 4);
        *(float4*)bgv = *(const float4*)(bg + f); *(float4*)(bgv + 4) = *(const float4*)(bg + f + 4);
        *(float4*)bbv = *(const float4*)(bb + f); *(float4*)(bbv + 4) = *(const float4*)(bb + f + 4);

        float o[8];
#pragma unroll
        for (int j = 0; j < 8; ++j) {
            float v = (a[j] * sc + cbv[j] - bmv[j]) * rsqrtf(bvv[j] + EPSB) * bgv[j] + bbv[j];
            o[j] = fmaxf(v, 0.f);
        }
        if (prev) {
            float4 p0 = *(const float4*)(prev + (size_t)node * DH + f);
            float4 p1 = *(const float4*)(prev + (size_t)node * DH + f + 4);
            o[0] += p0.x; o[1] += p0.y; o[2] += p0.z; o[3] += p0.w;
            o[4] += p1.x; o[5] += p1.y; o[6] += p1.z; o[7] += p1.w;
        }
        *(float4*)(feat + (size_t)node * DH + f)     = make_float4(o[0], o[1], o[2], o[3]);
        *(float4*)(feat + (size_t)node * DH + f + 4) = make_float4(o[4], o[5], o[6], o[7]);

        // stage bf16 hi/lo into LDS for the MFMA phase
        unsigned short hA[8], lA[8];
#pragma unroll
        for (int j = 0; j < 8; ++j) {
            unsigned short h = f2bf(o[j]);
            hA[j] = h; lA[j] = f2bf(o[j] - bf2f(h));
        }
        *(ushort4*)(Ah + nb * LDAP + f)     = make_ushort4(hA[0], hA[1], hA[2], hA[3]);
        *(ushort4*)(Ah + nb * LDAP + f + 4) = make_ushort4(hA[4], hA[5], hA[6], hA[7]);
        *(ushort4*)(Al + nb * LDAP + f)     = make_ushort4(lA[0], lA[1], lA[2], lA[3]);
        *(ushort4*)(Al + nb * LDAP + f + 4) = make_ushort4(lA[4], lA[5], lA[6], lA[7]);
    }
    __syncthreads();

    // ---- MFMA phase: hs_next = dinv * (feat @ W) for this block's 16 rows ----
    const int lane = tid & 63, wave = tid >> 6;
    const int r15 = lane & 15, quad = lane >> 4;

    f32x4 acc[2];
    acc[0] = (f32x4){0.f, 0.f, 0.f, 0.f};
    acc[1] = (f32x4){0.f, 0.f, 0.f, 0.f};

#pragma unroll
    for (int s = 0; s < 4; ++s) {
        short8 ah = *(const short8*)(Ah + r15 * LDAP + s * 32 + quad * 8);
        short8 al = *(const short8*)(Al + r15 * LDAP + s * 32 + quad * 8);
#pragma unroll
        for (int j = 0; j < 2; ++j) {
            int ntg = wave * 2 + j;
            int nh = ntg >> 2, nt = ntg & 3;
            short8 wh = *(const short8*)(Wf + ((((nh * 2 + 0) * 4 + s) * 4 + nt) * 512) + lane * 8);
            short8 wl = *(const short8*)(Wf + ((((nh * 2 + 1) * 4 + s) * 4 + nt) * 512) + lane * 8);
            acc[j] = __builtin_amdgcn_mfma_f32_16x16x32_bf16(ah, wh, acc[j], 0, 0, 0);
            acc[j] = __builtin_amdgcn_mfma_f32_16x16x32_bf16(ah, wl, acc[j], 0, 0, 0);
            acc[j] = __builtin_amdgcn_mfma_f32_16x16x32_bf16(al, wh, acc[j], 0, 0, 0);
        }
    }

    float dv[4];
#pragma unroll
    for (int reg = 0; reg < 4; ++reg) {
        int row = nodeBase + quad * 4 + reg;
        dv[reg] = (row < N) ? dinv[row] : 0.f;
    }
#pragma unroll
    for (int j = 0; j < 2; ++j) {
        int col = (wave * 2 + j) * 16 + r15;
#pragma unroll
        for (int reg = 0; reg < 4; ++reg) {
            int row = nodeBase + quad * 4 + reg;
            if (row < N)
                hs_next[(size_t)row * DH + col] = f2bf(acc[j][reg] * dv[reg]);
        }
    }
}

// ---------------- final gather (layer 2): no MFMA, in-place feat update ----------------

__launch_bounds__(256)
__global__ void k_gather_fin(const unsigned short* __restrict__ hs,
                             const int2* __restrict__ rowinfo,
                             const int* __restrict__ csr_src,
                             const float* __restrict__ dinv,
                             const float* __restrict__ cb, const float* __restrict__ bm,
                             const float* __restrict__ bv, const float* __restrict__ bg,
                             const float* __restrict__ bb,
                             const float* __restrict__ prev,    // residual (may alias feat)
                             float* __restrict__ feat, int N)
{
    const int node = (blockIdx.x * blockDim.x + threadIdx.x) >> 4;
    const int lh = threadIdx.x & 15;
    if (node >= N) return;
    const int f = lh * 8;
    int2 ri = rowinfo[node];

    const uint4* hsv = (const uint4*)hs;
    float a[8];
    {
        uint4 sv = hsv[(size_t)node * 16 + lh];
        a[0] = blo(sv.x); a[1] = bhi(sv.x); a[2] = blo(sv.y); a[3] = bhi(sv.y);
        a[4] = blo(sv.z); a[5] = bhi(sv.z); a[6] = blo(sv.w); a[7] = bhi(sv.w);
    }
    for (int base = ri.x; base < ri.y; base += 16) {
        int cnt = ri.y - base; if (cnt > 16) cnt = 16;
        int idx = (lh < cnt) ? csr_src[base + lh] : 0;
        int i = 0;
        for (; i + 4 <= cnt; i += 4) {
            int s0 = __shfl(idx, i,     16), s1 = __shfl(idx, i + 1, 16);
            int s2 = __shfl(idx, i + 2, 16), s3 = __shfl(idx, i + 3, 16);
            uint4 v0 = hsv[(size_t)s0 * 16 + lh];
            uint4 v1 = hsv[(size_t)s1 * 16 + lh];
            uint4 v2 = hsv[(size_t)s2 * 16 + lh];
            uint4 v3 = hsv[(size_t)s3 * 16 + lh];
            a[0] += (blo(v0.x) + blo(v1.x)) + (blo(v2.x) + blo(v3.x));
            a[1] += (bhi(v0.x) + bhi(v1.x)) + (bhi(v2.x) + bhi(v3.x));
            a[2] += (blo(v0.y) + blo(v1.y)) + (blo(v2.y) + blo(v3.y));
            a[3] += (bhi(v0.y) + bhi(v1.y)) + (bhi(v2.y) + bhi(v3.y));
            a[4] += (blo(v0.z) + blo(v1.z)) + (blo(v2.z) + blo(v3.z));
            a[5] += (bhi(v0.z) + bhi(v1.z)) + (bhi(v2.z) + bhi(v3.z));
            a[6] += (blo(v0.w) + blo(v1.w)) + (blo(v2.w) + blo(v3.w));
            a[7] += (bhi(v0.w) + bhi(v1.w)) + (bhi(v2.w) + bhi(v3.w));
        }
        for (; i < cnt; ++i) {
            int s = __shfl(idx, i, 16);
            uint4 v = hsv[(size_t)s * 16 + lh];
            a[0] += blo(v.x); a[1] += bhi(v.x); a[2] += blo(v.y); a[3] += bhi(v.y);
            a[4] += blo(v.z); a[5] += bhi(v.z); a[6] += blo(v.w); a[7] += bhi(v.w);
        }
    }

    const float sc = dinv[node];
    float cbv[8], bmv[8], bvv[8], bgv[8], bbv[8];
    *(float4*)cbv = *(const float4*)(cb + f); *(float4*)(cbv + 4) = *(const float4*)(cb + f + 4);
    *(float4*)bmv = *(const float4*)(bm + f); *(float4*)(bmv + 4) = *(const float4*)(bm + f + 4);
    *(float4*)bvv = *(const float4*)(bv + f); *(float4*)(bvv + 4) = *(const float4*)(bv + f + 4);
    *(float4*)bgv = *(const float4*)(bg + f); *(float4*)(bgv + 4) = *(const float4*)(bg + f + 4);
    *(float4*)bbv = *(const float4*)(bb + f); *(float4*)(bbv + 4) = *(const float4*)(bb + f + 4);

    float4 p0 = *(const float4*)(prev + (size_t)node * DH + f);
    float4 p1 = *(const float4*)(prev + (size_t)node * DH + f + 4);
    float o[8];
#pragma unroll
    for (int j = 0; j < 8; ++j) {
        float v = (a[j] * sc + cbv[j] - bmv[j]) * rsqrtf(bvv[j] + EPSB) * bgv[j] + bbv[j];
        o[j] = fmaxf(v, 0.f);
    }
    o[0] += p0.x; o[1] += p0.y; o[2] += p0.z; o[3] += p0.w;
    o[4] += p1.x; o[5] += p1.y; o[6] += p1.z; o[7] += p1.w;

    *(float4*)(feat + (size_t)node * DH + f)     = make_float4(o[0], o[1], o[2], o[3]);
    *(float4*)(feat + (size_t)node * DH + f + 4) = make_float4(o[4], o[5], o[6], o[7]);
}

// ---------------- fused pool (mean+max) + 3-layer MLP head (fp32 input) ----------------

__launch_bounds__(256)
__global__ void k_pool_mlp(const float* __restrict__ x, const int* __restrict__ starts,
                           const float* __restrict__ L1w, const float* __restrict__ L1b,
                           const float* __restrict__ L2w, const float* __restrict__ L2b,
                           const float* __restrict__ L3w, const float* __restrict__ L3b,
                           float* __restrict__ out)
{
    int g = blockIdx.x, t = threadIdx.x;
    int s0 = starts[g], s1 = starts[g + 1];
    const int rg = t >> 6;            // 0..3
    const int tc = t & 63;
    const int fc = tc * 2;            // 0..126

    float sA = 0.f, sB = 0.f;
    float mA = -INFINITY, mB = -INFINITY;
    for (int i = s0 + rg; i < s1; i += 4) {
        float2 v = *(const float2*)(x + (size_t)i * DH + fc);
        sA += v.x; sB += v.y;
        mA = fmaxf(mA, v.x); mB = fmaxf(mB, v.y);
    }

    __shared__ float ps[4][128];
    __shared__ float pm[4][128];
    ps[rg][fc] = sA; ps[rg][fc + 1] = sB;
    pm[rg][fc] = mA; pm[rg][fc + 1] = mB;
    __syncthreads();

    __shared__ float h[256];
    if (rg == 0) {
        float inv = 1.f / (float)(s1 - s0);
#pragma unroll
        for (int j = 0; j < 2; ++j) {
            int fi = fc + j;
            h[fi] = ((ps[0][fi] + ps[1][fi]) + (ps[2][fi] + ps[3][fi])) * inv;
            h[128 + fi] = fmaxf(fmaxf(pm[0][fi], pm[1][fi]), fmaxf(pm[2][fi], pm[3][fi]));
        }
    }
    __syncthreads();

    __shared__ float h1[128];
    if (t < 128) {
        float a = L1b[t];
        for (int k = 0; k < 256; ++k) a += h[k] * L1w[k * DH + t];
        h1[t] = fmaxf(a, 0.f);
    }
    __syncthreads();

    __shared__ float h2[64];
    if (t < 64) {
        float a2 = L2b[t];
        for (int k = 0; k < 128; ++k) a2 += h1[k] * L2w[k * 64 + t];
        h2[t] = fmaxf(a2, 0.f);
    }
    __syncthreads();

    if (t < 64) {
        float p = h2[t] * L3w[t];
#pragma unroll
        for (int off = 32; off > 0; off >>= 1) p += __shfl_down(p, off, 64);
        if (t == 0) out[g] = p + L3b[0];
    }
}

// ---------------- launch ----------------

static inline char* align16(char* p) {
    return (char*)(((uintptr_t)p + 15) & ~(uintptr_t)15);
}

extern "C" void kernel_launch(void* const* d_in, const int* in_sizes, int n_in,
                              void* d_out, int out_size, void* d_ws, size_t ws_size,
                              hipStream_t stream)
{
    const float* x     = (const float*)d_in[0];
    const int*   ei    = (const int*)d_in[1];
    const int*   batch = (const int*)d_in[2];
    const int N = in_sizes[0] / DH;
    const int E = in_sizes[1] / 2;
    const int G = out_size;
    const int* src = ei;
    const int* dst = ei + E;

    const float* W[3]  = {(const float*)d_in[3],  (const float*)d_in[9],  (const float*)d_in[15]};
    const float* cb[3] = {(const float*)d_in[4],  (const float*)d_in[10], (const float*)d_in[16]};
    const float* bg[3] = {(const float*)d_in[5],  (const float*)d_in[11], (const float*)d_in[17]};
    const float* bt[3] = {(const float*)d_in[6],  (const float*)d_in[12], (const float*)d_in[18]};
    const float* bm[3] = {(const float*)d_in[7],  (const float*)d_in[13], (const float*)d_in[19]};
    const float* bv[3] = {(const float*)d_in[8],  (const float*)d_in[14], (const float*)d_in[20]};
    const float* L1w = (const float*)d_in[21]; const float* L1b = (const float*)d_in[22];
    const float* L2w = (const float*)d_in[23]; const float* L2b = (const float*)d_in[24];
    const float* L3w = (const float*)d_in[25]; const float* L3b = (const float*)d_in[26];

    char* wsp = (char*)d_ws;
    size_t featB = (size_t)N * DH * sizeof(float);           // 51.2 MB
    size_t hsB   = (size_t)N * DH * sizeof(unsigned short);  // 25.6 MB
    float* F_A = (float*)wsp; wsp += featB;
    float* F_B = (float*)wsp; wsp += featB;
    unsigned short* HS0 = (unsigned short*)F_B;              // alias: dead before F_B written
    unsigned short* HS1 = (unsigned short*)wsp; wsp += hsB;
    unsigned short* HS2 = (unsigned short*)wsp; wsp += hsB;
    unsigned short* Wfrag = (unsigned short*)wsp; wsp += 3 * 65536;
    int2*  rowinfo = (int2*)wsp;  wsp += (size_t)N * sizeof(int2);
    float* dinv    = (float*)wsp; wsp += (size_t)N * sizeof(float);
    int*   starts  = (int*)wsp;   wsp = align16(wsp + (size_t)(G + 1) * sizeof(int));
    int*   gcur    = (int*)wsp;   wsp = align16(wsp + (size_t)MAXB * sizeof(int));
    int*   bbuf    = (int*)wsp;   wsp += (size_t)MAXB * BCAP * sizeof(int);   // 8.5 MB, csr in-place

    const int NB = (N + 127) >> 7;
    const int nblkA = 512;
    const int chunk = (E + nblkA - 1) / nblkA;

    hipMemsetAsync(gcur, 0, (size_t)NB * sizeof(int), stream);
    k_bucketA<<<nblkA + 48, 256, 0, stream>>>(src, dst, gcur, bbuf, batch, starts,
                                              W[0], W[1], W[2], Wfrag,
                                              E, NB, chunk, N, G);
    k_bfinal <<<NB, 256, 0, stream>>>(gcur, bbuf, rowinfo, dinv, N);

    int gemmGrid = (N + 63) / 64;
    int gathGrid = ((size_t)N * 16 + 255) / 256;

    // L0: gemm0(x) -> HS0(@F_B); gather_mm(HS0, prev=null, feat=F_A, W1) -> HS1
    // L1: gather_mm(HS1, prev=F_A, feat=F_B, W2) -> HS2
    // L2: gather_fin(HS2, prev=F_B, feat=F_B in-place)
    k_gemm0<<<gemmGrid, 256, 0, stream>>>(x, Wfrag, dinv, HS0, N);
    k_gather_mm<<<gathGrid, 256, 0, stream>>>(HS0, rowinfo, bbuf, dinv,
                                              cb[0], bm[0], bv[0], bg[0], bt[0],
                                              nullptr, F_A, Wfrag + 32768, HS1, N);
    k_gather_mm<<<gathGrid, 256, 0, stream>>>(HS1, rowinfo, bbuf, dinv,
                                              cb[1], bm[1], bv[1], bg[1], bt[1],
                                              F_A, F_B, Wfrag + 65536, HS2, N);
    k_gather_fin<<<gathGrid, 256, 0, stream>>>(HS2, rowinfo, bbuf, dinv,
                                               cb[2], bm[2], bv[2], bg[2], bt[2],
                                               F_B, F_B, N);

    k_pool_mlp<<<G, 256, 0, stream>>>(F_B, starts, L1w, L1b, L2w, L2b, L3w, L3b,
                                      (float*)d_out);
}